// Round 9
// baseline (82983.502 us; speedup 1.0000x reference)
//
#include <hip/hip_runtime.h>

// LSTMRecursiveModel: B=16, L=96, H=256, NL=2, O=32. 3168 sequential steps.
// Single-XCD persistent kernel: 32 WGs x 512 thr, 1 WG/CU (LDS-forced), on the
// first XCD to collect 32 WGs (R5/R7-proven claim). Phase p = L0(p) || L1(p-1).
//
// Round 9: proven primitives ONLY (R6/R8 sc0-asm kernels both hung: sc0 load
// does NOT reliably bypass L1 on gfx950 -> stale-flag deadlock).
//  - h/pred data: PLAIN loads/stores (write-through L1 -> home-XCD L2).
//  - barrier: R7's per-WG flag (agent-atomic store + 32-lane atomic poll,
//    MALL-served but tiny volume) + __builtin_amdgcn_fence(ACQUIRE, "agent")
//    by wave 0 after poll success: invalidates this CU's L1 so next phase's
//    plain staging loads observe the L2's fresh h. Final __syncthreads orders
//    waves 1-7 behind the invalidate. Release side needs no wbl2: producers'
//    write-through stores are in the shared L2 once __syncthreads drains vmcnt
//    (compiler emits s_waitcnt vmcnt(0) before s_barrier).
//  - compute structure byte-identical to R7 (absmax 0.0): LDS-staged h,
//    fold-reduce (36 shfl), VGPR-pinned weights, per-wave column ownership.

#define NWORK 32
#define NLAUNCH 256
#define LASTP 3169
#define BSTRIDE 290
#define CSTRIDE 18
#define H1OFF 4640      // 16*290
#define XOFF 9280       // x stage base; lds total 9296 floats

typedef float fx4 __attribute__((ext_vector_type(4)));

__device__ __forceinline__ float sigm(float x) { return 1.0f / (1.0f + expf(-x)); }

// ws float layout: h0buf[2][16][256]@0, h1buf@8192, predbuf[32][16]@16384,
// flags(32 u32, 64B-strided)@17024, arr[8]@17600, home@17608
__global__ void init_kernel(float* __restrict__ out, float* __restrict__ ws) {
  int i = blockIdx.x * blockDim.x + threadIdx.x;
  if (i < 16 * 96) out[i] = 0.0f;
  for (int j = i; j < 17608; j += gridDim.x * blockDim.x) ws[j] = 0.0f;
  if (i == 0) ((unsigned*)ws)[17608] = 0xFFFFFFFFu;
}

extern "C" __global__ __launch_bounds__(512, 2) void lstm_x9(
    const float* __restrict__ x_enc,
    const float* __restrict__ Wih0, const float* __restrict__ Whh0,
    const float* __restrict__ bih0, const float* __restrict__ bhh0,
    const float* __restrict__ Wih1, const float* __restrict__ Whh1,
    const float* __restrict__ bih1, const float* __restrict__ bhh1,
    const float* __restrict__ fc_w, const float* __restrict__ fc_b,
    float* __restrict__ out, float* __restrict__ ws) {
  const int tid = threadIdx.x;
  __shared__ int s_rank;
  extern __shared__ float lds[];

  unsigned* flags = (unsigned*)(ws + 17024);
  unsigned* arr = (unsigned*)(ws + 17600);
  unsigned* home = (unsigned*)(ws + 17608);
  float* predbuf = ws + 16384;

  // ---- claim: first XCD to collect 32 WGs wins (R5/R7-proven) ----
  if (tid == 0) {
    unsigned xcc;
    asm volatile("s_getreg_b32 %0, hwreg(HW_REG_XCC_ID)" : "=s"(xcc));
    xcc &= 7u;
    unsigned idx = __hip_atomic_fetch_add(&arr[xcc], 1u, __ATOMIC_ACQ_REL,
                                          __HIP_MEMORY_SCOPE_AGENT);
    int rank = -1;
    if (idx < NWORK) {
      if (idx == NWORK - 1) {
        unsigned expv = 0xFFFFFFFFu;
        __hip_atomic_compare_exchange_strong(home, &expv, xcc, __ATOMIC_ACQ_REL,
                                             __ATOMIC_RELAXED, __HIP_MEMORY_SCOPE_AGENT);
      }
      unsigned hv;
      while ((hv = __hip_atomic_load(home, __ATOMIC_RELAXED,
                                     __HIP_MEMORY_SCOPE_AGENT)) == 0xFFFFFFFFu) {}
      if (hv == xcc) rank = (int)idx;
    }
    s_rank = rank;
  }
  __syncthreads();
  const int rank = s_rank;
  if (rank < 0) return;

  const int wv = tid >> 6, lane = tid & 63;
  const int g = lane & 1, kl = lane >> 1;    // batch-group (8 b), k-slice (32)
  const int bown = g * 8 + (kl & 7);
  const int cc = rank * 8 + wv;              // owned column, both layers

  // ---- stationary weights -> VGPRs, pinned (96 floats/lane) ----
  fx4 W0[2][4], W1[4][4];
  float bias0[4], xw0[4], bias1[4];
#pragma unroll
  for (int q = 0; q < 4; ++q) {
    int row = q * 256 + cc;
    W0[0][q] = *(const fx4*)(Whh0 + row * 256 + kl * 4);
    W0[1][q] = *(const fx4*)(Whh0 + row * 256 + 128 + kl * 4);
    W1[0][q] = *(const fx4*)(Wih1 + row * 256 + kl * 4);
    W1[1][q] = *(const fx4*)(Wih1 + row * 256 + 128 + kl * 4);
    W1[2][q] = *(const fx4*)(Whh1 + row * 256 + kl * 4);
    W1[3][q] = *(const fx4*)(Whh1 + row * 256 + 128 + kl * 4);
    bias0[q] = bih0[row] + bhh0[row];
    xw0[q] = Wih0[row];                      // Wih0 is (1024,1)
    bias1[q] = bih1[row] + bhh1[row];
  }
#pragma unroll
  for (int q = 0; q < 4; ++q) {
    asm volatile("" : "+v"(W0[0][q]), "+v"(W0[1][q]));
    asm volatile("" : "+v"(W1[0][q]), "+v"(W1[1][q]), "+v"(W1[2][q]), "+v"(W1[3][q]));
  }

  const int k0 = kl & 1, k1 = (kl >> 1) & 1, k2 = (kl >> 2) & 1;

  // fold-reduce: a[4][8] (gate,bb) over 32 kl-lanes -> aq[4] for bb=kl&7.
  auto fold = [&](float (&a)[4][8], float (&aq)[4]) {
    float b2[4][4];
#pragma unroll
    for (int q = 0; q < 4; ++q)
#pragma unroll
      for (int u = 0; u < 4; ++u) {
        float snd = k0 ? a[q][2 * u] : a[q][2 * u + 1];
        float rcv = __shfl_xor(snd, 2);
        b2[q][u] = (k0 ? a[q][2 * u + 1] : a[q][2 * u]) + rcv;
      }
    float c2[4][2];
#pragma unroll
    for (int q = 0; q < 4; ++q)
#pragma unroll
      for (int u = 0; u < 2; ++u) {
        float snd = k1 ? b2[q][2 * u] : b2[q][2 * u + 1];
        float rcv = __shfl_xor(snd, 4);
        c2[q][u] = (k1 ? b2[q][2 * u + 1] : b2[q][2 * u]) + rcv;
      }
#pragma unroll
    for (int q = 0; q < 4; ++q) {
      float snd = k2 ? c2[q][0] : c2[q][1];
      float rcv = __shfl_xor(snd, 8);
      aq[q] = (k2 ? c2[q][1] : c2[q][0]) + rcv;
      aq[q] += __shfl_xor(aq[q], 16);
      aq[q] += __shfl_xor(aq[q], 32);
    }
  };

  double cs0 = 0.0, cs1 = 0.0;

  for (int p = 0; p <= LASTP; ++p) {
    const float* h0prev = ws + ((p + 1) & 1) * 4096;
    float* h0cur = ws + (p & 1) * 4096;
    const float* h1prev = ws + 8192 + (p & 1) * 4096;
    float* h1cur = ws + 8192 + ((p + 1) & 1) * 4096;

    // ---- stage h0prev + h1prev -> LDS: 8 plain b64 loads (L1 was
    // invalidated by last phase's acquire fence; lines come from L2) ----
    unsigned long long sv[8];
#pragma unroll
    for (int m = 0; m < 8; ++m) {
      int i = tid + m * 512;   // 0..4095
      const float* src = (i < 2048) ? (h0prev + 2 * i) : (h1prev + 2 * (i - 2048));
      sv[m] = *(const unsigned long long*)src;
    }
    float xs = 0.0f;
    const bool dox = (tid < 16) && (p <= 3167);
    if (dox) {
      int s = p;
      if (s < 96) {
        xs = x_enc[tid * 96 + s];
      } else {
        int sk = s - 96;
        int k = sk / 96;
        int t = sk - k * 96;
        xs = (t < 96 - k) ? x_enc[tid * 96 + k + t]
                          : predbuf[(t - 96 + k) * 16 + tid];
      }
    }
#pragma unroll
    for (int m = 0; m < 8; ++m) {
      int i = tid + m * 512;
      int ii = (i < 2048) ? i : (i - 2048);
      int b = ii >> 7, r = ii & 127;
      int idx = ((i < 2048) ? 0 : H1OFF) + b * BSTRIDE + (r >> 3) * CSTRIDE + 2 * (r & 7);
      union { unsigned long long u; float2 f; } c; c.u = sv[m];
      *(float2*)&lds[idx] = c.f;
    }
    if (dox) lds[XOFF + tid] = xs;
    __syncthreads();

    const int cbase = (kl >> 2) * CSTRIDE + 4 * (kl & 3);

    // ---- layer 0, step p ----
    if (p <= 3167) {
      float a[4][8];
#pragma unroll
      for (int q = 0; q < 4; ++q)
#pragma unroll
        for (int bb = 0; bb < 8; ++bb) a[q][bb] = 0.0f;
#pragma unroll
      for (int bb = 0; bb < 8; ++bb) {
        const float* hb = lds + (g * 8 + bb) * BSTRIDE;
        float2 x0 = *(const float2*)(hb + cbase);
        float2 x1 = *(const float2*)(hb + cbase + 2);
        float2 x2 = *(const float2*)(hb + 8 * CSTRIDE + cbase);
        float2 x3 = *(const float2*)(hb + 8 * CSTRIDE + cbase + 2);
#pragma unroll
        for (int q = 0; q < 4; ++q) {
          a[q][bb] += W0[0][q][0] * x0.x + W0[0][q][1] * x0.y +
                      W0[0][q][2] * x1.x + W0[0][q][3] * x1.y +
                      W0[1][q][0] * x2.x + W0[1][q][1] * x2.y +
                      W0[1][q][2] * x3.x + W0[1][q][3] * x3.y;
        }
      }
      float aq[4];
      fold(a, aq);
      float xv = lds[XOFF + bown];
      float gI = aq[0] + xv * xw0[0] + bias0[0];
      float gF = aq[1] + xv * xw0[1] + bias0[1];
      float gG = aq[2] + xv * xw0[2] + bias0[2];
      float gO = aq[3] + xv * xw0[3] + bias0[3];
      double cn = (double)sigm(gF) * cs0 + (double)(sigm(gI) * tanhf(gG));
      float hn = sigm(gO) * tanhf((float)cn);
      cs0 = cn;
      if (kl < 8) h0cur[bown * 256 + cc] = hn;
    }

    // ---- layer 1, step p-1 ----
    if (p >= 1 && p <= 3168) {
      float a[4][8];
#pragma unroll
      for (int q = 0; q < 4; ++q)
#pragma unroll
        for (int bb = 0; bb < 8; ++bb) a[q][bb] = 0.0f;
#pragma unroll
      for (int bb = 0; bb < 8; ++bb) {
        const float* hb0 = lds + (g * 8 + bb) * BSTRIDE;
        const float* hb1 = hb0 + H1OFF;
        float2 x0 = *(const float2*)(hb0 + cbase);
        float2 x1 = *(const float2*)(hb0 + cbase + 2);
        float2 x2 = *(const float2*)(hb0 + 8 * CSTRIDE + cbase);
        float2 x3 = *(const float2*)(hb0 + 8 * CSTRIDE + cbase + 2);
        float2 y0 = *(const float2*)(hb1 + cbase);
        float2 y1 = *(const float2*)(hb1 + cbase + 2);
        float2 y2 = *(const float2*)(hb1 + 8 * CSTRIDE + cbase);
        float2 y3 = *(const float2*)(hb1 + 8 * CSTRIDE + cbase + 2);
#pragma unroll
        for (int q = 0; q < 4; ++q) {
          a[q][bb] += W1[0][q][0] * x0.x + W1[0][q][1] * x0.y +
                      W1[0][q][2] * x1.x + W1[0][q][3] * x1.y +
                      W1[1][q][0] * x2.x + W1[1][q][1] * x2.y +
                      W1[1][q][2] * x3.x + W1[1][q][3] * x3.y +
                      W1[2][q][0] * y0.x + W1[2][q][1] * y0.y +
                      W1[2][q][2] * y1.x + W1[2][q][3] * y1.y +
                      W1[3][q][0] * y2.x + W1[3][q][1] * y2.y +
                      W1[3][q][2] * y3.x + W1[3][q][3] * y3.y;
        }
      }
      float aq[4];
      fold(a, aq);
      float gI = aq[0] + bias1[0];
      float gF = aq[1] + bias1[1];
      float gG = aq[2] + bias1[2];
      float gO = aq[3] + bias1[3];
      double cn = (double)sigm(gF) * cs1 + (double)(sigm(gI) * tanhf(gG));
      float hn = sigm(gO) * tanhf((float)cn);
      cs1 = cn;
      if (kl < 8) h1cur[bown * 256 + cc] = hn;
    }

    // ---- prediction: h1(191+96jp) = staged h1s this phase ----
    if (rank == 0 && wv == 0 && p >= 193 && ((p - 193) % 96) == 0) {
      int jp = (p - 193) / 96;
      if (jp < 32) {
        int pb = lane & 15, q4 = lane >> 4;
        float acc = 0.0f;
#pragma unroll
        for (int j = 0; j < 32; ++j) {
          int kk = q4 * 64 + 2 * j;
          float2 hv = *(const float2*)&lds[H1OFF + pb * BSTRIDE +
                                           (kk >> 4) * CSTRIDE + (kk & 15)];
          acc += hv.x * fc_w[kk] + hv.y * fc_w[kk + 1];
        }
        acc += __shfl_xor(acc, 16);
        acc += __shfl_xor(acc, 32);
        if (q4 == 0) {
          float pv = acc + fc_b[0];
          predbuf[jp * 16 + pb] = pv;
          out[pb * 96 + jp] = pv;
        }
      }
    }

    // ---- barrier: flag store + poll (agent atomics, R7-proven) + L1
    // acquire-invalidate so next phase's plain loads see fresh L2 data ----
    __syncthreads();   // compiler drains vmcnt(0): h stores are in L2
    if (tid == 0) {
      __hip_atomic_store(&flags[rank * 16], (unsigned)(p + 1), __ATOMIC_RELAXED,
                         __HIP_MEMORY_SCOPE_AGENT);
    }
    if (wv == 0) {
      const bool active = lane < NWORK;
      const unsigned* myf = flags + (active ? lane : 0) * 16;
      const unsigned tgt = (unsigned)(p + 1);
      while (!__all(!active ||
                    __hip_atomic_load(myf, __ATOMIC_RELAXED,
                                      __HIP_MEMORY_SCOPE_AGENT) >= tgt)) {
      }
      __builtin_amdgcn_fence(__ATOMIC_ACQUIRE, "agent");   // L1 invalidate
    }
    __syncthreads();   // waves 1-7 ordered behind the invalidate
  }
}

extern "C" void kernel_launch(void* const* d_in, const int* in_sizes, int n_in,
                              void* d_out, int out_size, void* d_ws, size_t ws_size,
                              hipStream_t stream) {
  const float* x_enc = (const float*)d_in[0];
  const float* Wih0 = (const float*)d_in[4];
  const float* Whh0 = (const float*)d_in[5];
  const float* bih0 = (const float*)d_in[6];
  const float* bhh0 = (const float*)d_in[7];
  const float* Wih1 = (const float*)d_in[8];
  const float* Whh1 = (const float*)d_in[9];
  const float* bih1 = (const float*)d_in[10];
  const float* bhh1 = (const float*)d_in[11];
  const float* fc_w = (const float*)d_in[12];
  const float* fc_b = (const float*)d_in[13];
  float* out = (float*)d_out;
  float* ws = (float*)d_ws;

  hipLaunchKernelGGL(init_kernel, dim3(8), dim3(256), 0, stream, out, ws);

  const int ldsBytes = 82944;   // ~37KB used; >80KB forces 1 WG/CU residency
  static int attrSet = 0;
  if (!attrSet) {
    (void)hipFuncSetAttribute((const void*)lstm_x9,
                              hipFuncAttributeMaxDynamicSharedMemorySize, ldsBytes);
    attrSet = 1;
  }

  hipLaunchKernelGGL(lstm_x9, dim3(NLAUNCH), dim3(512), ldsBytes, stream,
                     x_enc, Wih0, Whh0, bih0, bhh0, Wih1, Whh1, bih1, bhh1,
                     fc_w, fc_b, out, ws);
}